// Round 5
// baseline (944.799 us; speedup 1.0000x reference)
//
#include <hip/hip_runtime.h>

// NetEdge GNN round 5: linearity trick — gather z = xc@W1 (64 f/edge) instead
// of xc (96 f/edge); xc never materialized; shfl-broadcast MLPs; 16-wide
// gather unroll. CSR/CSC build via two-level MSD binning (round 3).

namespace {
constexpr int N  = 50000;    // nodes
constexpr int E  = 1600000;  // edges
constexpr int G  = 256;      // graphs
constexpr int EC = 32;       // edge channels
constexpr int H  = 64;       // hidden / node channels
constexpr int D  = 96;       // concat dim (64 + 32)
constexpr int OUTC = 10;     // classes
constexpr int NB = (N + 255) / 256;   // 196 coarse buckets (node >> 8)
constexpr int CHUNK = 4096;           // edges per pass-1 block
}

// ---- pass 1a: coarse histograms ----
__global__ __launch_bounds__(256) void k_p1hist(const int* __restrict__ row,
                                                const int* __restrict__ col,
                                                int* __restrict__ cntR,
                                                int* __restrict__ cntC) {
    __shared__ int hR[NB], hC[NB];
    for (int i = threadIdx.x; i < NB; i += 256) { hR[i] = 0; hC[i] = 0; }
    __syncthreads();
    int base = blockIdx.x * CHUNK;
    int end = min(base + CHUNK, E);
    for (int e = base + threadIdx.x; e < end; e += 256) {
        atomicAdd(&hR[row[e] >> 8], 1);
        atomicAdd(&hC[col[e] >> 8], 1);
    }
    __syncthreads();
    for (int i = threadIdx.x; i < NB; i += 256) {
        if (hR[i]) atomicAdd(&cntR[i], hR[i]);
        if (hC[i]) atomicAdd(&cntC[i], hC[i]);
    }
}

// ---- pass 1b: scan bucket counts -> bases + cursors; off[N]=E ----
__global__ __launch_bounds__(256) void k_bscan(const int* __restrict__ cntR,
                                               const int* __restrict__ cntC,
                                               int* __restrict__ baseR, int* __restrict__ baseC,
                                               int* __restrict__ curR,  int* __restrict__ curC,
                                               int* __restrict__ offR,  int* __restrict__ offC) {
    __shared__ int sR[256], sC[256];
    int t = threadIdx.x;
    sR[t] = (t < NB) ? cntR[t] : 0;
    sC[t] = (t < NB) ? cntC[t] : 0;
    __syncthreads();
    for (int d = 1; d < 256; d <<= 1) {
        int vR = sR[t], vC = sC[t];
        int uR = (t >= d) ? sR[t - d] : 0;
        int uC = (t >= d) ? sC[t - d] : 0;
        __syncthreads();
        sR[t] = vR + uR; sC[t] = vC + uC;
        __syncthreads();
    }
    if (t < NB) {
        int bR = (t == 0) ? 0 : sR[t - 1];
        int bC = (t == 0) ? 0 : sC[t - 1];
        baseR[t] = bR; curR[t] = bR;
        baseC[t] = bC; curC[t] = bC;
    }
    if (t == 0) { offR[N] = E; offC[N] = E; }
}

// ---- pass 1c: coarse scatter of packed (key<<32|val) ----
__global__ __launch_bounds__(256) void k_p1scat(const int* __restrict__ row,
                                                const int* __restrict__ col,
                                                int* __restrict__ curR, int* __restrict__ curC,
                                                unsigned long long* __restrict__ kvR,
                                                unsigned long long* __restrict__ kvC) {
    __shared__ int hR[NB], hC[NB];
    __shared__ int cR[NB], cC[NB];
    for (int i = threadIdx.x; i < NB; i += 256) { hR[i] = 0; hC[i] = 0; }
    __syncthreads();
    int base = blockIdx.x * CHUNK;
    int end = min(base + CHUNK, E);
    for (int e = base + threadIdx.x; e < end; e += 256) {
        atomicAdd(&hR[row[e] >> 8], 1);
        atomicAdd(&hC[col[e] >> 8], 1);
    }
    __syncthreads();
    for (int i = threadIdx.x; i < NB; i += 256) {
        cR[i] = hR[i] ? atomicAdd(&curR[i], hR[i]) : 0;
        cC[i] = hC[i] ? atomicAdd(&curC[i], hC[i]) : 0;
    }
    __syncthreads();
    for (int e = base + threadIdx.x; e < end; e += 256) {
        int r = row[e], c = col[e];
        int pR = atomicAdd(&cR[r >> 8], 1);
        kvR[pR] = ((unsigned long long)(unsigned)r << 32) | (unsigned)e;
        int pC = atomicAdd(&cC[c >> 8], 1);
        kvC[pC] = ((unsigned long long)(unsigned)c << 32) | (unsigned)r;
    }
}

// ---- pass 2: per-bucket fine bin ----
__global__ __launch_bounds__(256) void k_p2(const unsigned long long* __restrict__ kvR,
                                            const unsigned long long* __restrict__ kvC,
                                            const int* __restrict__ baseR, const int* __restrict__ baseC,
                                            const int* __restrict__ cntR,  const int* __restrict__ cntC,
                                            int* __restrict__ offR, int* __restrict__ offC,
                                            int* __restrict__ eid, int* __restrict__ srcrow) {
    bool isC = blockIdx.x >= NB;
    int b = isC ? blockIdx.x - NB : blockIdx.x;
    const unsigned long long* kv = isC ? kvC : kvR;
    int sbase = isC ? baseC[b] : baseR[b];
    int scnt  = isC ? cntC[b]  : cntR[b];
    int* off  = isC ? offC : offR;
    int* outv = isC ? srcrow : eid;

    __shared__ int hist[256], s[256], cur[256];
    int t = threadIdx.x;
    hist[t] = 0;
    __syncthreads();
    for (int i = sbase + t; i < sbase + scnt; i += 256) {
        atomicAdd(&hist[(int)(kv[i] >> 32) & 255], 1);
    }
    __syncthreads();
    s[t] = hist[t];
    __syncthreads();
    for (int d = 1; d < 256; d <<= 1) {
        int v = s[t];
        int u = (t >= d) ? s[t - d] : 0;
        __syncthreads();
        s[t] = v + u;
        __syncthreads();
    }
    int excl = (t == 0) ? 0 : s[t - 1];
    cur[t] = sbase + excl;
    int node = (b << 8) + t;
    if (node < N) off[node] = sbase + excl;
    __syncthreads();
    for (int i = sbase + t; i < sbase + scnt; i += 256) {
        unsigned long long p = kv[i];
        int lk = (int)(p >> 32) & 255;
        int pos = atomicAdd(&cur[lk], 1);
        outv[pos] = (int)(p & 0xffffffffu);
    }
}

// ---- ea[n] = sum over outgoing edges of edge_attr; 16 edges in flight ----
__global__ __launch_bounds__(256) void k_ea_gather(const float* __restrict__ edge_attr,
                                                   const int* __restrict__ eid,
                                                   const int* __restrict__ offR,
                                                   float* __restrict__ ea) {
    int n = blockIdx.x * 8 + (threadIdx.x >> 5);
    int c = threadIdx.x & 31;
    if (n >= N) return;
    int b = offR[n], e_end = offR[n + 1];
    float s = 0.f;
    for (int i0 = b; i0 < e_end; i0 += 16) {
        int cnt = min(16, e_end - i0);
        int ev = eid[min(i0 + (c & 15), e_end - 1)];
        if (cnt == 16) {
            float v[16];
            #pragma unroll
            for (int j = 0; j < 16; ++j) {
                int e = __shfl(ev, j, 32);
                v[j] = edge_attr[(size_t)e * EC + c];
            }
            #pragma unroll
            for (int j = 0; j < 16; ++j) s += v[j];
        } else {
            for (int j = 0; j < cnt; ++j) {
                int e = __shfl(ev, j, 32);
                s += edge_attr[(size_t)e * EC + c];
            }
        }
    }
    ea[(size_t)n * EC + c] = s;
}

// ---- zrel = [head‖ea] @ relW1 (no bias); hroot = relu([head‖ea] @ rootW1 + b) ----
// wave per node; input broadcast via shfl; weights in LDS.
__global__ __launch_bounds__(256) void k_mlp1v(const float* __restrict__ head,
                        const float* __restrict__ ea,
                        const float* __restrict__ relW1,
                        const float* __restrict__ rootW1, const float* __restrict__ rootb1,
                        float* __restrict__ zrel, float* __restrict__ hroot) {
    __shared__ float sWz[D * H];
    __shared__ float sWh[D * H];
    for (int i = threadIdx.x; i < D * H; i += 256) {
        sWz[i] = relW1[i];
        sWh[i] = rootW1[i];
    }
    __syncthreads();
    int lane = threadIdx.x & 63;
    int wid  = threadIdx.x >> 6;
    int nwaves = gridDim.x * 4;
    float bo = rootb1[lane];
    for (int n = blockIdx.x * 4 + wid; n < N; n += nwaves) {
        float h0 = head[(size_t)n * H + lane];
        float h1 = (lane < EC) ? ea[(size_t)n * EC + lane] : 0.f;
        float accz = 0.f, acch = bo;
        #pragma unroll 8
        for (int k = 0; k < H; ++k) {
            float v = __shfl(h0, k);
            accz += v * sWz[k * H + lane];
            acch += v * sWh[k * H + lane];
        }
        #pragma unroll 8
        for (int k = 0; k < EC; ++k) {
            float v = __shfl(h1, k);
            accz += v * sWz[(H + k) * H + lane];
            acch += v * sWh[(H + k) * H + lane];
        }
        zrel[(size_t)n * H + lane]  = accz;
        hroot[(size_t)n * H + lane] = fmaxf(acch, 0.f);
    }
}

// ---- hrel[n] = relu(sum over incoming edges of zrel[src] + relb1) ----
// wave per node, lane = channel; 16 edges in flight.
__global__ __launch_bounds__(256) void k_gprop(const float* __restrict__ zrel,
                                               const int* __restrict__ srcrow,
                                               const int* __restrict__ offC,
                                               const float* __restrict__ relb1,
                                               float* __restrict__ hrel) {
    int n = blockIdx.x * 4 + (threadIdx.x >> 6);
    int lane = threadIdx.x & 63;
    if (n >= N) return;
    int b = offC[n], e_end = offC[n + 1];
    float a = 0.f;
    for (int i0 = b; i0 < e_end; i0 += 16) {
        int cnt = min(16, e_end - i0);
        int rv = srcrow[min(i0 + (lane & 15), e_end - 1)];
        if (cnt == 16) {
            float v[16];
            #pragma unroll
            for (int j = 0; j < 16; ++j) {
                int rj = __shfl(rv, j);
                v[j] = zrel[(size_t)rj * H + lane];
            }
            #pragma unroll
            for (int j = 0; j < 16; ++j) a += v[j];
        } else {
            for (int j = 0; j < cnt; ++j) {
                int rj = __shfl(rv, j);
                a += zrel[(size_t)rj * H + lane];
            }
        }
    }
    hrel[(size_t)n * H + lane] = fmaxf(a + relb1[lane], 0.f);
}

// ---- xout = relu(hrel @ relW2 + hroot @ rootW2 + b) ----
__global__ __launch_bounds__(256) void k_mlp2(const float* __restrict__ hrel,
                       const float* __restrict__ hroot,
                       const float* __restrict__ relW2, const float* __restrict__ relb2,
                       const float* __restrict__ rootW2, const float* __restrict__ rootb2,
                       float* __restrict__ xout) {
    __shared__ float sWr[H * H];
    __shared__ float sWo[H * H];
    for (int i = threadIdx.x; i < H * H; i += 256) {
        sWr[i] = relW2[i];
        sWo[i] = rootW2[i];
    }
    __syncthreads();
    int lane = threadIdx.x & 63;
    int wid  = threadIdx.x >> 6;
    int nwaves = gridDim.x * 4;
    float b = relb2[lane] + rootb2[lane];
    for (int n = blockIdx.x * 4 + wid; n < N; n += nwaves) {
        float hr = hrel[(size_t)n * H + lane];
        float ho = hroot[(size_t)n * H + lane];
        float acc = b;
        #pragma unroll 8
        for (int k = 0; k < H; ++k) {
            acc += __shfl(hr, k) * sWr[k * H + lane]
                 + __shfl(ho, k) * sWo[k * H + lane];
        }
        xout[(size_t)n * H + lane] = fmaxf(acc, 0.f);
    }
}

// ---- pooled[batch[n]] += x[n], 16-node register pre-reduce (batch sorted) ----
__global__ __launch_bounds__(256) void k_pool(const float* __restrict__ x,
                                              const int* __restrict__ batch,
                                              float* __restrict__ pooled) {
    int c = threadIdx.x & 63;
    int grp = blockIdx.x * 4 + (threadIdx.x >> 6);
    int n0 = grp * 16;
    if (n0 >= N) return;
    int nend = min(n0 + 16, N);
    int curb = batch[n0];
    float acc = 0.f;
    for (int n = n0; n < nend; ++n) {
        int b = batch[n];
        if (b != curb) {
            atomicAdd(&pooled[curb * H + c], acc);
            acc = 0.f;
            curb = b;
        }
        acc += x[(size_t)n * H + c];
    }
    atomicAdd(&pooled[curb * H + c], acc);
}

// ---- out = relu(pooled @ finW1 + finb1) @ finW2 + finb2 ----
__global__ void k_final(const float* __restrict__ pooled,
                        const float* __restrict__ W1, const float* __restrict__ b1,
                        const float* __restrict__ W2, const float* __restrict__ b2,
                        float* __restrict__ out) {
    __shared__ float h[H];
    int g = blockIdx.x;
    int j = threadIdx.x;
    const float* p = pooled + (size_t)g * H;
    float acc = b1[j];
    #pragma unroll 8
    for (int k = 0; k < H; ++k) acc += p[k] * W1[k * H + j];
    h[j] = fmaxf(acc, 0.f);
    __syncthreads();
    if (j < OUTC) {
        float o = b2[j];
        #pragma unroll 8
        for (int k = 0; k < H; ++k) o += h[k] * W2[k * OUTC + j];
        out[(size_t)g * OUTC + j] = o;
    }
}

extern "C" void kernel_launch(void* const* d_in, const int* in_sizes, int n_in,
                              void* d_out, int out_size, void* d_ws, size_t ws_size,
                              hipStream_t stream) {
    const float* x         = (const float*)d_in[0];
    const float* edge_attr = (const float*)d_in[1];
    const float* P[16];
    for (int i = 0; i < 16; ++i) P[i] = (const float*)d_in[2 + i];
    const float* finW1 = (const float*)d_in[18];
    const float* finb1 = (const float*)d_in[19];
    const float* finW2 = (const float*)d_in[20];
    const float* finb2 = (const float*)d_in[21];
    const int* row   = (const int*)d_in[22];
    const int* col   = row + E;
    const int* batch = (const int*)d_in[23];
    float* out = (float*)d_out;
    (void)ws_size; (void)n_in; (void)in_sizes; (void)out_size;

    // ---- workspace ----
    float* fw = (float*)d_ws;
    float* zrel   = fw;  fw += (size_t)N * H;   // aliased by kvR during build
    float* hroot  = fw;  fw += (size_t)N * H;   // aliased by kvR during build
    float* hrel   = fw;  fw += (size_t)N * H;   // aliased by kvC during build
    float* x1     = fw;  fw += (size_t)N * H;   // aliased by kvC during build
    float* ea     = fw;  fw += (size_t)N * EC;
    float* pooled = fw;  fw += (size_t)G * H;
    int* iw = (int*)fw;
    int* cntR   = iw;  iw += NB;
    int* cntC   = iw;  iw += NB;
    int* baseR  = iw;  iw += NB;
    int* baseC  = iw;  iw += NB;
    int* curR   = iw;  iw += NB;
    int* curC   = iw;  iw += NB;
    int* offR   = iw;  iw += N + 1;
    int* offC   = iw;  iw += N + 1;
    int* eid    = iw;  iw += E;
    int* srcrow = iw;  iw += E;
    // kv arrays (E x 8B each) alias the node float arrays: only live during build
    unsigned long long* kvR = (unsigned long long*)zrel;   // covers zrel+hroot
    unsigned long long* kvC = (unsigned long long*)hrel;   // covers hrel+x1

    // ---- build CSR/CSC ----
    hipMemsetAsync(cntR, 0, 2 * (size_t)NB * sizeof(int), stream);
    hipMemsetAsync(pooled, 0, (size_t)G * H * sizeof(float), stream);
    int p1grid = (E + CHUNK - 1) / CHUNK;
    k_p1hist<<<p1grid, 256, 0, stream>>>(row, col, cntR, cntC);
    k_bscan<<<1, 256, 0, stream>>>(cntR, cntC, baseR, baseC, curR, curC, offR, offC);
    k_p1scat<<<p1grid, 256, 0, stream>>>(row, col, curR, curC, kvR, kvC);
    k_p2<<<2 * NB, 256, 0, stream>>>(kvR, kvC, baseR, baseC, cntR, cntC,
                                     offR, offC, eid, srcrow);

    // ---- shared edge aggregation ----
    k_ea_gather<<<(N + 7) / 8, 256, 0, stream>>>(edge_attr, eid, offR, ea);

    // ---- layer 1 ----
    k_mlp1v<<<512, 256, 0, stream>>>(x, ea, P[0], P[4], P[5], zrel, hroot);
    k_gprop<<<(N + 3) / 4, 256, 0, stream>>>(zrel, srcrow, offC, P[1], hrel);
    k_mlp2<<<512, 256, 0, stream>>>(hrel, hroot, P[2], P[3], P[6], P[7], x1);

    // ---- layer 2 ----
    k_mlp1v<<<512, 256, 0, stream>>>(x1, ea, P[8], P[12], P[13], zrel, hroot);
    k_gprop<<<(N + 3) / 4, 256, 0, stream>>>(zrel, srcrow, offC, P[9], hrel);
    k_mlp2<<<512, 256, 0, stream>>>(hrel, hroot, P[10], P[11], P[14], P[15], x1);

    // ---- pool + head ----
    k_pool<<<(N / 16 + 3) / 4, 256, 0, stream>>>(x1, batch, pooled);
    k_final<<<G, 64, 0, stream>>>(pooled, finW1, finb1, finW2, finb2, out);
}

// Round 6
// 878.198 us; speedup vs baseline: 1.0758x; 1.0758x over previous
//
#include <hip/hip_runtime.h>

// NetEdge GNN round 6: float4 gathers (4 edges per wave-load in propagate,
// 8 in ea), 32 edges in flight per wave; gprop+bias+relu+W2-MLP fused into
// one kernel per layer. Build (two-level MSD binning) unchanged from r3.

namespace {
constexpr int N  = 50000;    // nodes
constexpr int E  = 1600000;  // edges
constexpr int G  = 256;      // graphs
constexpr int EC = 32;       // edge channels
constexpr int H  = 64;       // hidden / node channels
constexpr int D  = 96;       // concat dim (64 + 32)
constexpr int OUTC = 10;     // classes
constexpr int NB = (N + 255) / 256;   // 196 coarse buckets (node >> 8)
constexpr int CHUNK = 4096;           // edges per pass-1 block
}

// ---- pass 1a: coarse histograms ----
__global__ __launch_bounds__(256) void k_p1hist(const int* __restrict__ row,
                                                const int* __restrict__ col,
                                                int* __restrict__ cntR,
                                                int* __restrict__ cntC) {
    __shared__ int hR[NB], hC[NB];
    for (int i = threadIdx.x; i < NB; i += 256) { hR[i] = 0; hC[i] = 0; }
    __syncthreads();
    int base = blockIdx.x * CHUNK;
    int end = min(base + CHUNK, E);
    for (int e = base + threadIdx.x; e < end; e += 256) {
        atomicAdd(&hR[row[e] >> 8], 1);
        atomicAdd(&hC[col[e] >> 8], 1);
    }
    __syncthreads();
    for (int i = threadIdx.x; i < NB; i += 256) {
        if (hR[i]) atomicAdd(&cntR[i], hR[i]);
        if (hC[i]) atomicAdd(&cntC[i], hC[i]);
    }
}

// ---- pass 1b: scan bucket counts -> bases + cursors; off[N]=E ----
__global__ __launch_bounds__(256) void k_bscan(const int* __restrict__ cntR,
                                               const int* __restrict__ cntC,
                                               int* __restrict__ baseR, int* __restrict__ baseC,
                                               int* __restrict__ curR,  int* __restrict__ curC,
                                               int* __restrict__ offR,  int* __restrict__ offC) {
    __shared__ int sR[256], sC[256];
    int t = threadIdx.x;
    sR[t] = (t < NB) ? cntR[t] : 0;
    sC[t] = (t < NB) ? cntC[t] : 0;
    __syncthreads();
    for (int d = 1; d < 256; d <<= 1) {
        int vR = sR[t], vC = sC[t];
        int uR = (t >= d) ? sR[t - d] : 0;
        int uC = (t >= d) ? sC[t - d] : 0;
        __syncthreads();
        sR[t] = vR + uR; sC[t] = vC + uC;
        __syncthreads();
    }
    if (t < NB) {
        int bR = (t == 0) ? 0 : sR[t - 1];
        int bC = (t == 0) ? 0 : sC[t - 1];
        baseR[t] = bR; curR[t] = bR;
        baseC[t] = bC; curC[t] = bC;
    }
    if (t == 0) { offR[N] = E; offC[N] = E; }
}

// ---- pass 1c: coarse scatter of packed (key<<32|val) ----
__global__ __launch_bounds__(256) void k_p1scat(const int* __restrict__ row,
                                                const int* __restrict__ col,
                                                int* __restrict__ curR, int* __restrict__ curC,
                                                unsigned long long* __restrict__ kvR,
                                                unsigned long long* __restrict__ kvC) {
    __shared__ int hR[NB], hC[NB];
    __shared__ int cR[NB], cC[NB];
    for (int i = threadIdx.x; i < NB; i += 256) { hR[i] = 0; hC[i] = 0; }
    __syncthreads();
    int base = blockIdx.x * CHUNK;
    int end = min(base + CHUNK, E);
    for (int e = base + threadIdx.x; e < end; e += 256) {
        atomicAdd(&hR[row[e] >> 8], 1);
        atomicAdd(&hC[col[e] >> 8], 1);
    }
    __syncthreads();
    for (int i = threadIdx.x; i < NB; i += 256) {
        cR[i] = hR[i] ? atomicAdd(&curR[i], hR[i]) : 0;
        cC[i] = hC[i] ? atomicAdd(&curC[i], hC[i]) : 0;
    }
    __syncthreads();
    for (int e = base + threadIdx.x; e < end; e += 256) {
        int r = row[e], c = col[e];
        int pR = atomicAdd(&cR[r >> 8], 1);
        kvR[pR] = ((unsigned long long)(unsigned)r << 32) | (unsigned)e;
        int pC = atomicAdd(&cC[c >> 8], 1);
        kvC[pC] = ((unsigned long long)(unsigned)c << 32) | (unsigned)r;
    }
}

// ---- pass 2: per-bucket fine bin ----
__global__ __launch_bounds__(256) void k_p2(const unsigned long long* __restrict__ kvR,
                                            const unsigned long long* __restrict__ kvC,
                                            const int* __restrict__ baseR, const int* __restrict__ baseC,
                                            const int* __restrict__ cntR,  const int* __restrict__ cntC,
                                            int* __restrict__ offR, int* __restrict__ offC,
                                            int* __restrict__ eid, int* __restrict__ srcrow) {
    bool isC = blockIdx.x >= NB;
    int b = isC ? blockIdx.x - NB : blockIdx.x;
    const unsigned long long* kv = isC ? kvC : kvR;
    int sbase = isC ? baseC[b] : baseR[b];
    int scnt  = isC ? cntC[b]  : cntR[b];
    int* off  = isC ? offC : offR;
    int* outv = isC ? srcrow : eid;

    __shared__ int hist[256], s[256], cur[256];
    int t = threadIdx.x;
    hist[t] = 0;
    __syncthreads();
    for (int i = sbase + t; i < sbase + scnt; i += 256) {
        atomicAdd(&hist[(int)(kv[i] >> 32) & 255], 1);
    }
    __syncthreads();
    s[t] = hist[t];
    __syncthreads();
    for (int d = 1; d < 256; d <<= 1) {
        int v = s[t];
        int u = (t >= d) ? s[t - d] : 0;
        __syncthreads();
        s[t] = v + u;
        __syncthreads();
    }
    int excl = (t == 0) ? 0 : s[t - 1];
    cur[t] = sbase + excl;
    int node = (b << 8) + t;
    if (node < N) off[node] = sbase + excl;
    __syncthreads();
    for (int i = sbase + t; i < sbase + scnt; i += 256) {
        unsigned long long p = kv[i];
        int lk = (int)(p >> 32) & 255;
        int pos = atomicAdd(&cur[lk], 1);
        outv[pos] = (int)(p & 0xffffffffu);
    }
}

// ---- ea[n] = sum of edge_attr over outgoing edges; float4, 8 edges/load ----
// wave per node: grp = lane>>3 (edge in group of 8), q = lane&7 (float4 chunk).
__global__ __launch_bounds__(256) void k_ea_gather(const float4* __restrict__ ea4_in,
                                                   const int* __restrict__ eid,
                                                   const int* __restrict__ offR,
                                                   float4* __restrict__ ea_out) {
    int n = blockIdx.x * 4 + (threadIdx.x >> 6);
    int lane = threadIdx.x & 63;
    if (n >= N) return;
    int grp = lane >> 3;
    int q   = lane & 7;
    int b = offR[n], e_end = offR[n + 1];
    float4 acc = make_float4(0.f, 0.f, 0.f, 0.f);
    for (int i0 = b; i0 < e_end; i0 += 32) {
        int lim = e_end - i0;
        int ev = eid[min(i0 + lane, e_end - 1)];
        if (lim >= 32) {
            float4 v[4];
            #pragma unroll
            for (int s = 0; s < 4; ++s) {
                int e = __shfl(ev, s * 8 + grp);
                v[s] = ea4_in[(size_t)e * 8 + q];
            }
            #pragma unroll
            for (int s = 0; s < 4; ++s) {
                acc.x += v[s].x; acc.y += v[s].y; acc.z += v[s].z; acc.w += v[s].w;
            }
        } else {
            int steps = (lim + 7) >> 3;
            for (int s = 0; s < steps; ++s) {
                int eidx = s * 8 + grp;
                int e = __shfl(ev, eidx);
                float4 v = ea4_in[(size_t)e * 8 + q];
                if (eidx < lim) {
                    acc.x += v.x; acc.y += v.y; acc.z += v.z; acc.w += v.w;
                }
            }
        }
    }
    // reduce across the 8 edge-groups (lanes q, q+8, ..., q+56)
    #pragma unroll
    for (int m = 8; m <= 32; m <<= 1) {
        acc.x += __shfl_xor(acc.x, m);
        acc.y += __shfl_xor(acc.y, m);
        acc.z += __shfl_xor(acc.z, m);
        acc.w += __shfl_xor(acc.w, m);
    }
    if (lane < 8) ea_out[(size_t)n * 8 + q] = acc;
}

// ---- zrel = [head‖ea] @ relW1 (no bias); hroot = relu([head‖ea] @ rootW1 + b) ----
__global__ __launch_bounds__(256) void k_mlp1v(const float* __restrict__ head,
                        const float* __restrict__ ea,
                        const float* __restrict__ relW1,
                        const float* __restrict__ rootW1, const float* __restrict__ rootb1,
                        float* __restrict__ zrel, float* __restrict__ hroot) {
    __shared__ float sWz[D * H];
    __shared__ float sWh[D * H];
    for (int i = threadIdx.x; i < D * H; i += 256) {
        sWz[i] = relW1[i];
        sWh[i] = rootW1[i];
    }
    __syncthreads();
    int lane = threadIdx.x & 63;
    int wid  = threadIdx.x >> 6;
    int nwaves = gridDim.x * 4;
    float bo = rootb1[lane];
    for (int n = blockIdx.x * 4 + wid; n < N; n += nwaves) {
        float h0 = head[(size_t)n * H + lane];
        float h1 = (lane < EC) ? ea[(size_t)n * EC + lane] : 0.f;
        float accz = 0.f, acch = bo;
        #pragma unroll 8
        for (int k = 0; k < H; ++k) {
            float v = __shfl(h0, k);
            accz += v * sWz[k * H + lane];
            acch += v * sWh[k * H + lane];
        }
        #pragma unroll 8
        for (int k = 0; k < EC; ++k) {
            float v = __shfl(h1, k);
            accz += v * sWz[(H + k) * H + lane];
            acch += v * sWh[(H + k) * H + lane];
        }
        zrel[(size_t)n * H + lane]  = accz;
        hroot[(size_t)n * H + lane] = fmaxf(acch, 0.f);
    }
}

// ---- fused: agg = gather-sum zrel[src] (float4, 4 edges/load, 32 in flight);
//      hrel = relu(agg + relb1); xout = relu(hrel@relW2 + hroot@rootW2 + b2) ----
__global__ __launch_bounds__(256) void k_gfuse(const float4* __restrict__ z4,
                        const int* __restrict__ srcrow,
                        const int* __restrict__ offC,
                        const float4* __restrict__ relb1_4,
                        const float* __restrict__ hroot,
                        const float* __restrict__ relW2, const float* __restrict__ relb2,
                        const float* __restrict__ rootW2, const float* __restrict__ rootb2,
                        float* __restrict__ xout) {
    __shared__ float sWr[H * H];
    __shared__ float sWo[H * H];
    for (int i = threadIdx.x; i < H * H; i += 256) {
        sWr[i] = relW2[i];
        sWo[i] = rootW2[i];
    }
    __syncthreads();
    int lane = threadIdx.x & 63;
    int wid  = threadIdx.x >> 6;
    int nwaves = gridDim.x * 4;
    int grp = lane >> 4;   // edge subgroup 0..3
    int q   = lane & 15;   // float4 chunk of the 64-ch row
    float b2 = relb2[lane] + rootb2[lane];
    float4 b1 = relb1_4[q];
    for (int n = blockIdx.x * 4 + wid; n < N; n += nwaves) {
        int b = offC[n], e_end = offC[n + 1];
        float4 acc = make_float4(0.f, 0.f, 0.f, 0.f);
        for (int i0 = b; i0 < e_end; i0 += 32) {
            int lim = e_end - i0;
            int rv = srcrow[min(i0 + lane, e_end - 1)];
            if (lim >= 32) {
                float4 v[8];
                #pragma unroll
                for (int s = 0; s < 8; ++s) {
                    int src = __shfl(rv, s * 4 + grp);
                    v[s] = z4[(size_t)src * 16 + q];
                }
                #pragma unroll
                for (int s = 0; s < 8; ++s) {
                    acc.x += v[s].x; acc.y += v[s].y; acc.z += v[s].z; acc.w += v[s].w;
                }
            } else {
                int steps = (lim + 3) >> 2;
                for (int s = 0; s < steps; ++s) {
                    int eidx = s * 4 + grp;
                    int src = __shfl(rv, eidx);
                    float4 v = z4[(size_t)src * 16 + q];
                    if (eidx < lim) {
                        acc.x += v.x; acc.y += v.y; acc.z += v.z; acc.w += v.w;
                    }
                }
            }
        }
        // reduce across 4 edge-groups (lanes q, q+16, q+32, q+48)
        #pragma unroll
        for (int m = 16; m <= 32; m <<= 1) {
            acc.x += __shfl_xor(acc.x, m);
            acc.y += __shfl_xor(acc.y, m);
            acc.z += __shfl_xor(acc.z, m);
            acc.w += __shfl_xor(acc.w, m);
        }
        // hrel chunk q (4 channels), replicated in all 4 groups
        float4 h;
        h.x = fmaxf(acc.x + b1.x, 0.f);
        h.y = fmaxf(acc.y + b1.y, 0.f);
        h.z = fmaxf(acc.z + b1.z, 0.f);
        h.w = fmaxf(acc.w + b1.w, 0.f);
        float ho = hroot[(size_t)n * H + lane];
        // xout[lane] = sum_k hrel[k]*Wr[k][lane] + hroot[k]*Wo[k][lane] + b2
        float o = b2;
        #pragma unroll 8
        for (int k = 0; k < H; ++k) {
            int src_lane = k >> 2;
            float hk;
            switch (k & 3) {
                case 0: hk = __shfl(h.x, src_lane); break;
                case 1: hk = __shfl(h.y, src_lane); break;
                case 2: hk = __shfl(h.z, src_lane); break;
                default: hk = __shfl(h.w, src_lane); break;
            }
            o += hk * sWr[k * H + lane] + __shfl(ho, k) * sWo[k * H + lane];
        }
        xout[(size_t)n * H + lane] = fmaxf(o, 0.f);
    }
}

// ---- pooled[batch[n]] += x[n], 16-node register pre-reduce (batch sorted) ----
__global__ __launch_bounds__(256) void k_pool(const float* __restrict__ x,
                                              const int* __restrict__ batch,
                                              float* __restrict__ pooled) {
    int c = threadIdx.x & 63;
    int grp = blockIdx.x * 4 + (threadIdx.x >> 6);
    int n0 = grp * 16;
    if (n0 >= N) return;
    int nend = min(n0 + 16, N);
    int curb = batch[n0];
    float acc = 0.f;
    for (int n = n0; n < nend; ++n) {
        int b = batch[n];
        if (b != curb) {
            atomicAdd(&pooled[curb * H + c], acc);
            acc = 0.f;
            curb = b;
        }
        acc += x[(size_t)n * H + c];
    }
    atomicAdd(&pooled[curb * H + c], acc);
}

// ---- out = relu(pooled @ finW1 + finb1) @ finW2 + finb2 ----
__global__ void k_final(const float* __restrict__ pooled,
                        const float* __restrict__ W1, const float* __restrict__ b1,
                        const float* __restrict__ W2, const float* __restrict__ b2,
                        float* __restrict__ out) {
    __shared__ float h[H];
    int g = blockIdx.x;
    int j = threadIdx.x;
    const float* p = pooled + (size_t)g * H;
    float acc = b1[j];
    #pragma unroll 8
    for (int k = 0; k < H; ++k) acc += p[k] * W1[k * H + j];
    h[j] = fmaxf(acc, 0.f);
    __syncthreads();
    if (j < OUTC) {
        float o = b2[j];
        #pragma unroll 8
        for (int k = 0; k < H; ++k) o += h[k] * W2[k * OUTC + j];
        out[(size_t)g * OUTC + j] = o;
    }
}

extern "C" void kernel_launch(void* const* d_in, const int* in_sizes, int n_in,
                              void* d_out, int out_size, void* d_ws, size_t ws_size,
                              hipStream_t stream) {
    const float* x         = (const float*)d_in[0];
    const float* edge_attr = (const float*)d_in[1];
    const float* P[16];
    for (int i = 0; i < 16; ++i) P[i] = (const float*)d_in[2 + i];
    const float* finW1 = (const float*)d_in[18];
    const float* finb1 = (const float*)d_in[19];
    const float* finW2 = (const float*)d_in[20];
    const float* finb2 = (const float*)d_in[21];
    const int* row   = (const int*)d_in[22];
    const int* col   = row + E;
    const int* batch = (const int*)d_in[23];
    float* out = (float*)d_out;
    (void)ws_size; (void)n_in; (void)in_sizes; (void)out_size;

    // ---- workspace ----
    float* fw = (float*)d_ws;
    float* zrel   = fw;  fw += (size_t)N * H;   // aliased by kvR during build
    float* hroot  = fw;  fw += (size_t)N * H;   // aliased by kvR during build
    float* x1     = fw;  fw += (size_t)N * H;   // aliased by kvC during build
    float* xpad   = fw;  fw += (size_t)N * H;   // aliased by kvC during build
    float* ea     = fw;  fw += (size_t)N * EC;
    float* pooled = fw;  fw += (size_t)G * H;
    int* iw = (int*)fw;
    int* cntR   = iw;  iw += NB;
    int* cntC   = iw;  iw += NB;
    int* baseR  = iw;  iw += NB;
    int* baseC  = iw;  iw += NB;
    int* curR   = iw;  iw += NB;
    int* curC   = iw;  iw += NB;
    int* offR   = iw;  iw += N + 1;
    int* offC   = iw;  iw += N + 1;
    int* eid    = iw;  iw += E;
    int* srcrow = iw;  iw += E;
    // kv arrays (E x 8B each) alias node float arrays (build-only lifetime)
    unsigned long long* kvR = (unsigned long long*)zrel;   // covers zrel+hroot
    unsigned long long* kvC = (unsigned long long*)x1;     // covers x1+xpad

    // ---- build CSR/CSC ----
    hipMemsetAsync(cntR, 0, 2 * (size_t)NB * sizeof(int), stream);
    hipMemsetAsync(pooled, 0, (size_t)G * H * sizeof(float), stream);
    int p1grid = (E + CHUNK - 1) / CHUNK;
    k_p1hist<<<p1grid, 256, 0, stream>>>(row, col, cntR, cntC);
    k_bscan<<<1, 256, 0, stream>>>(cntR, cntC, baseR, baseC, curR, curC, offR, offC);
    k_p1scat<<<p1grid, 256, 0, stream>>>(row, col, curR, curC, kvR, kvC);
    k_p2<<<2 * NB, 256, 0, stream>>>(kvR, kvC, baseR, baseC, cntR, cntC,
                                     offR, offC, eid, srcrow);

    // ---- shared edge aggregation ----
    k_ea_gather<<<(N + 3) / 4, 256, 0, stream>>>((const float4*)edge_attr, eid, offR,
                                                 (float4*)ea);

    // ---- layer 1 ----
    k_mlp1v<<<512, 256, 0, stream>>>(x, ea, P[0], P[4], P[5], zrel, hroot);
    k_gfuse<<<1024, 256, 0, stream>>>((const float4*)zrel, srcrow, offC,
                                      (const float4*)P[1], hroot,
                                      P[2], P[3], P[6], P[7], x1);

    // ---- layer 2 ----
    k_mlp1v<<<512, 256, 0, stream>>>(x1, ea, P[8], P[12], P[13], zrel, hroot);
    k_gfuse<<<1024, 256, 0, stream>>>((const float4*)zrel, srcrow, offC,
                                      (const float4*)P[9], hroot,
                                      P[10], P[11], P[14], P[15], x1);

    // ---- pool + head ----
    k_pool<<<(N / 16 + 3) / 4, 256, 0, stream>>>(x1, batch, pooled);
    k_final<<<G, 64, 0, stream>>>(pooled, finW1, finb1, finW2, finb2, out);
}